// Round 9
// baseline (2438.720 us; speedup 1.0000x reference)
//
#include <hip/hip_runtime.h>
#include <hip/hip_bf16.h>
#include <stdint.h>

typedef __bf16 bf16x8 __attribute__((ext_vector_type(8)));
typedef float f32x4 __attribute__((ext_vector_type(4)));
typedef unsigned short u16;
typedef unsigned short u16x4 __attribute__((ext_vector_type(4)));
typedef unsigned int u32;
typedef unsigned int u32x4 __attribute__((ext_vector_type(4)));
typedef unsigned long long u64;

#define B_  64
#define S_  256
#define I_  1024
#define H_  1024
#define NG  4096      /* 4*H */
#define M_  16384     /* S*B */

using gvoid_p = const __attribute__((address_space(1))) void*;
using lvoid_p = __attribute__((address_space(3))) void*;

__device__ __forceinline__ void gl_lds16(const void* g, void* l) {
  __builtin_amdgcn_global_load_lds((gvoid_p)g, (lvoid_p)l, 16, 0, 0);
}

__device__ __forceinline__ u16 f2bf(float f) {
  __hip_bfloat16 h = __float2bfloat16(f);
  union { __hip_bfloat16 h; u16 u; } c; c.h = h; return c.u;
}
__device__ __forceinline__ float bf2f(u16 u) {
  union { unsigned u; float f; } c; c.u = ((unsigned)u) << 16; return c.f;
}

// 8B LLC-coherent load (relaxed agent atomic). Also used for W pinning:
// atomics are NOT rematerializable, so values loaded this way stay resident.
__device__ __forceinline__ u64 ld8(const u64* p) {
  return __hip_atomic_load(p, __ATOMIC_RELAXED, __HIP_MEMORY_SCOPE_AGENT);
}

// ---- fp32 -> bf16 converts -------------------------------------------------
__global__ void cvt_x(const float* __restrict__ x, u16* __restrict__ xb) {
  int bid = blockIdx.x;            // = s*64 + b
  int b = bid & 63, s = bid >> 6;
  int t = threadIdx.x;
  float4 v = ((const float4*)(x + (size_t)b * (S_ * I_) + (size_t)s * I_))[t];
  u16x4 o;
  o[0] = f2bf(v.x); o[1] = f2bf(v.y); o[2] = f2bf(v.z); o[3] = f2bf(v.w);
  ((u16x4*)(xb + (size_t)bid * I_))[t] = o;
}

__global__ void cvt_w(const float* __restrict__ w, u16* __restrict__ wb) {
  size_t i = ((size_t)blockIdx.x * 256 + threadIdx.x) * 4;
  float4 v = *(const float4*)(w + i);
  u16x4 o;
  o[0] = f2bf(v.x); o[1] = f2bf(v.y); o[2] = f2bf(v.z); o[3] = f2bf(v.w);
  *(u16x4*)(wb + i) = o;
}

// w_i row (g*1024+c) -> permuted row (c*4+g): gemm emits gx with the 4 gates
// of one column adjacent (one 8B load/lane/step in the recurrence).
__global__ void cvt_w_perm(const float* __restrict__ w, u16* __restrict__ wb) {
  const int r = blockIdx.x;                 // source row 0..4095
  const int g = r >> 10, c = r & 1023;
  const int rp = c * 4 + g;
  float4 v = ((const float4*)(w + (size_t)r * I_))[threadIdx.x];
  u16x4 o;
  o[0] = f2bf(v.x); o[1] = f2bf(v.y); o[2] = f2bf(v.z); o[3] = f2bf(v.w);
  ((u16x4*)(wb + (size_t)rp * I_))[threadIdx.x] = o;
}

// ---- big input GEMM: gx[16384][4096] = X * WiP^T (row-major C) -------------
// Round-9 delta: XCD-aware blockIdx swizzle (bijective; nwg=4096 = 8*512) so
// consecutive tiles sharing A-rows/B-cols land on the same XCD L2. (+~10%
// on HBM-bound GEMM per catalog T1; attributable via this dispatch's dur.)
__global__ __launch_bounds__(256) void gemm_bt(const u16* __restrict__ A,
                                               const u16* __restrict__ BT,
                                               u16* __restrict__ C) {
  __shared__ u16 As[128 * 32];
  __shared__ u16 Bs[128 * 32];
  const int tid  = threadIdx.x;
  const int lane = tid & 63;
  const int wv   = tid >> 6;
  const int wm   = wv & 1, wn = wv >> 1;
  const int quad = lane >> 4, l16 = lane & 15;

  // XCD swizzle: grid = (32 x 128) = 4096 blocks; 4096 % 8 == 0 -> bijective
  int bid = blockIdx.y * 32 + blockIdx.x;
  bid = (bid & 7) * 512 + (bid >> 3);
  const int m0 = (bid >> 5) * 128;          // bid / 32
  const int n0 = (bid & 31) * 128;          // bid % 32

  const int c0i = tid, c1i = tid + 256;
  const int ar0 = c0i >> 2, ak0 = (c0i & 3) * 8;
  const int ar1 = c1i >> 2, ak1 = (c1i & 3) * 8;

  f32x4 acc[4][4] = {};

  for (int kt = 0; kt < 32; ++kt) {
    const int k0 = kt * 32;
    __syncthreads();
    gl_lds16(A + (size_t)(m0 + ar0) * I_ + k0 + ak0, &As[c0i * 8]);
    gl_lds16(A + (size_t)(m0 + ar1) * I_ + k0 + ak1, &As[c1i * 8]);
    gl_lds16(BT + (size_t)(n0 + ar0) * I_ + k0 + ak0, &Bs[c0i * 8]);
    gl_lds16(BT + (size_t)(n0 + ar1) * I_ + k0 + ak1, &Bs[c1i * 8]);
    __syncthreads();

    bf16x8 af[4], bfr[4];
#pragma unroll
    for (int mi = 0; mi < 4; ++mi)
      af[mi] = *(const bf16x8*)&As[(wm * 64 + mi * 16 + l16) * 32 + quad * 8];
#pragma unroll
    for (int ni = 0; ni < 4; ++ni)
      bfr[ni] = *(const bf16x8*)&Bs[(wn * 64 + ni * 16 + l16) * 32 + quad * 8];
#pragma unroll
    for (int mi = 0; mi < 4; ++mi)
#pragma unroll
      for (int ni = 0; ni < 4; ++ni)
        acc[mi][ni] = __builtin_amdgcn_mfma_f32_16x16x32_bf16(af[mi], bfr[ni], acc[mi][ni], 0, 0, 0);
  }

#pragma unroll
  for (int mi = 0; mi < 4; ++mi)
#pragma unroll
    for (int ni = 0; ni < 4; ++ni) {
      const int col = n0 + wn * 64 + ni * 16 + l16;
#pragma unroll
      for (int r = 0; r < 4; ++r) {
        const int row = m0 + wm * 64 + mi * 16 + quad * 4 + r;
        C[(size_t)row * NG + col] = f2bf(acc[mi][ni][r]);
      }
    }
}

// ---- persistent recurrent kernel -------------------------------------------
// ROUND-8 CHAMPION (979us), single protocol delta: PER-WAVE flags replace
// the block-wide drain barrier (#2). Each wave publishes its h slice, does a
// wave-local vmcnt(0), and its lane0 stores flags[q][cg4][v] — the flag
// releases when THAT wave's stores drain, not when the slowest wave reaches
// a barrier. Consumers poll 256 flags via ONE 16B sc0sc1 load per lane
// (4 flags/lane; same request count as before). One barrier per step.
//
// Safety without barrier #2:
//  - hs single-buffer: wave A starts stage(s+1) only after poll(s+1), which
//    requires its OWN block's 4 wave-flags >= s+2; a wave's flag advances
//    only after publish(s), which follows its GEMV(s) reads of hs. So no
//    wave can overwrite hs while a sibling still reads it.
//  - hbuf depth-2: flag >= s+1 from wave W implies W's stage(s-1) loads
//    drained (same vmcnt(0)), so writing hbuf[(s+1)&1] (= (s-1)&1) is safe.
// This isolates the per-wave-flag variable r7 confounded (8-wave shape,
// 8B-atomic stage, dual-u64 polls).
__global__ __launch_bounds__(256, 1) void lstm_rec(
    const u16* __restrict__ whb,     // [4096][1024] bf16 (gate-major rows)
    const u16* __restrict__ gxp,     // [(s*64+b)][c*4+g] bf16 (permuted cols)
    const float* __restrict__ b_i, const float* __restrict__ b_h,
    const float* __restrict__ h0, const float* __restrict__ c0,
    u16* hbuf,                       // [2][64][1024] bf16 (double buffer)
    u32* flags,                      // [4][64][4]; [q][cg4][v] = s+2 when h(s+1) out
    float* __restrict__ out) {       // hidden[64][256][1024], hN, cN
  const int tid = threadIdx.x, lane = tid & 63, v = tid >> 6;  // v 0..3
  const int quad = lane >> 4, l16 = lane & 15;
  const int blk = blockIdx.x;
  const int q = blk & 3, cg4 = blk >> 2;
  const int colbase = cg4 * 16 + v * 4;
  const int row = q * 16 + l16;            // batch row
  const int col = colbase + quad;          // h column

  __shared__ __align__(16) u16 hs[16 * 1024];  // 32 KB staged h (swizzled)

  float cst = c0[(size_t)row * H_ + col];
  float hl  = h0[(size_t)row * H_ + col];

  // init: h0 slice -> hbuf[0]; wave-local drain; per-wave flag = 1
  {
    float ha = __shfl_down(hl, 16);
    unsigned lo = (unsigned)f2bf(hl) | ((unsigned)f2bf(ha) << 16);
    unsigned p2 = __shfl_down(lo, 32);
    if (quad == 0) {
      u64 pp = (u64)lo | ((u64)p2 << 32);
      __hip_atomic_store((u64*)(hbuf + (size_t)row * H_ + colbase), pp,
                         __ATOMIC_RELAXED, __HIP_MEMORY_SCOPE_AGENT);
    }
    asm volatile("s_waitcnt vmcnt(0)" ::: "memory");
    if (lane == 0)
      __hip_atomic_store(&flags[(q * 64 + cg4) * 4 + v], 1u,
                         __ATOMIC_RELAXED, __HIP_MEMORY_SCOPE_AGENT);
  }

  f32x4 bias;
#pragma unroll
  for (int r = 0; r < 4; ++r)
    bias[r] = b_i[r * H_ + col] + b_h[r * H_ + col];

  // W_h fragments -> registers (atomic loads: compiler cannot remat them).
  // A-row m=l16 -> (gate = l16&3, col off = l16>>2); D rows m=quad*4+r give
  // (gate=r, col=colbase+quad).
  const int wrow = (l16 & 3) * H_ + colbase + (l16 >> 2);
  bf16x8 wf[32];
#pragma unroll
  for (int kt = 0; kt < 32; ++kt) {
    const u64* wp = (const u64*)(whb + (size_t)wrow * H_ + kt * 32 + quad * 8);
    union { u64 u[2]; bf16x8 v; } c;
    c.u[0] = ld8(wp);
    c.u[1] = ld8(wp + 1);
    wf[kt] = c.v;
  }

  const char* fptr = (const char*)(flags + (size_t)q * 256 + lane * 4);
  const char* hsb = (const char*)hs;
  const int swz = (l16 & 7) << 4;          // XOR swizzle (16B granules)

#pragma unroll 1
  for (int s = 0; s < S_; ++s) {
    // gx early (plain load, L2/LLC-resident)
    u16x4 gx4 = *(const u16x4*)(gxp + (size_t)(s * 64 + row) * NG + col * 4);

    // dataflow wait: each lane checks 4 per-wave flags of col-group `lane`
    // via one 16B coherent load (flags are monotone: stale read just retries)
    {
      const unsigned tgt = (unsigned)(s + 1);
      while (1) {
        u32x4 f;
        asm volatile("global_load_dwordx4 %0, %1, off sc0 sc1\n\t"
                     "s_waitcnt vmcnt(0)"
                     : "=v"(f) : "v"(fptr) : "memory");
        bool ok = (f[0] >= tgt) & (f[1] >= tgt) & (f[2] >= tgt) & (f[3] >= tgt);
        if (__all((int)ok)) break;
        __builtin_amdgcn_s_sleep(1);
      }
    }

    // stage h(s): wave v stages rows v*4..v*4+3 (8KB) -> swizzled LDS.
    // 16B coherent loads; data stable post-flag so no atomicity needed.
    {
      const char* srcb = (const char*)(hbuf + (size_t)(s & 1) * (B_ * H_)
                                            + (size_t)(q * 16 + v * 4) * H_);
      u32x4 stg[8];
#pragma unroll
      for (int i = 0; i < 4; ++i)
#pragma unroll
        for (int j = 0; j < 2; ++j)
          asm volatile("global_load_dwordx4 %0, %1, off sc0 sc1"
                       : "=v"(stg[i * 2 + j])
                       : "v"(srcb + (size_t)i * 2048 + (j * 64 + lane) * 16)
                       : "memory");
      asm volatile("s_waitcnt vmcnt(0)"
                   : "+v"(stg[0]), "+v"(stg[1]), "+v"(stg[2]), "+v"(stg[3]),
                     "+v"(stg[4]), "+v"(stg[5]), "+v"(stg[6]), "+v"(stg[7])
                   :: "memory");
      __builtin_amdgcn_sched_barrier(0);
#pragma unroll
      for (int i = 0; i < 4; ++i) {
        const int r = v * 4 + i;
#pragma unroll
        for (int j = 0; j < 2; ++j) {
          const int u = j * 64 + lane;
          *(u32x4*)((char*)hs + (size_t)r * 2048 + ((u * 16) ^ ((r & 7) << 4))) =
              stg[i * 2 + j];
        }
      }
    }
    __syncthreads();   // the ONLY barrier per step: stage visible to all

    // GEMV: acc[r] accumulates gate r at (row, col); 32 MFMAs, 4-way ILP
    f32x4 acc[4] = {};
#pragma unroll
    for (int kt = 0; kt < 32; ++kt) {
      bf16x8 bv = *(const bf16x8*)(hsb + l16 * 2048 + ((kt * 64 + quad * 16) ^ swz));
      acc[kt & 3] = __builtin_amdgcn_mfma_f32_16x16x32_bf16(wf[kt], bv, acc[kt & 3], 0, 0, 0);
    }

    f32x4 g4;
#pragma unroll
    for (int r = 0; r < 4; ++r)
      g4[r] = acc[0][r] + acc[1][r] + acc[2][r] + acc[3][r]
            + bias[r] + bf2f(gx4[r]);

    float iv = 1.f / (1.f + __expf(-g4[0]));
    float fv = 1.f / (1.f + __expf(-g4[1]));
    float gz = fminf(fmaxf(g4[2], -15.f), 15.f);
    float eg = __expf(2.f * gz);
    float gv = (eg - 1.f) / (eg + 1.f);
    float ov = 1.f / (1.f + __expf(-g4[3]));
    float cn = fv * cst + iv * gv;
    cst = cn;
    float cc = fminf(fmaxf(cn, -15.f), 15.f);
    float ec = __expf(2.f * cc);
    hl = ov * ((ec - 1.f) / (ec + 1.f));

    // publish h(s+1); wave-local drain; per-wave flag; out AFTER flag
    float ha = __shfl_down(hl, 16);                  // col+1
    unsigned lo = (unsigned)f2bf(hl) | ((unsigned)f2bf(ha) << 16);
    unsigned p2 = __shfl_down(lo, 32);               // cols +2,+3
    float o2 = __shfl_down(hl, 32);                  // col+2
    float o3 = __shfl_down(ha, 32);                  // col+3

    if (quad == 0) {
      u64 pp = (u64)lo | ((u64)p2 << 32);
      __hip_atomic_store(
          (u64*)(hbuf + (size_t)((s + 1) & 1) * (B_ * H_)
                      + (size_t)row * H_ + colbase),
          pp, __ATOMIC_RELAXED, __HIP_MEMORY_SCOPE_AGENT);
    }
    asm volatile("s_waitcnt vmcnt(0)" ::: "memory");
    if (lane == 0)
      __hip_atomic_store(&flags[(q * 64 + cg4) * 4 + v], (unsigned)(s + 2),
                         __ATOMIC_RELAXED, __HIP_MEMORY_SCOPE_AGENT);
    // out store AFTER flag: off the cross-block critical path, coalesced 16B
    if (quad == 0) {
      f32x4 ovv = { hl, ha, o2, o3 };
      __builtin_nontemporal_store(ovv,
          (f32x4*)(out + ((size_t)row * S_ + s) * H_ + colbase));
    }
  }

  // final hN, cN
  {
    const size_t base = (size_t)B_ * S_ * H_;
    out[base + (size_t)row * H_ + col] = hl;
    out[base + (size_t)B_ * H_ + (size_t)row * H_ + col] = cst;
  }
}

// ---- launch ----------------------------------------------------------------
extern "C" void kernel_launch(void* const* d_in, const int* in_sizes, int n_in,
                              void* d_out, int out_size, void* d_ws, size_t ws_size,
                              hipStream_t stream) {
  const float* x  = (const float*)d_in[0];
  const float* h0 = (const float*)d_in[1];
  const float* c0 = (const float*)d_in[2];
  const float* wi = (const float*)d_in[3];
  const float* wh = (const float*)d_in[4];
  const float* bi = (const float*)d_in[5];
  const float* bh = (const float*)d_in[6];
  float* out = (float*)d_out;

  char* ws = (char*)d_ws;
  u16* xb   = (u16*)(ws);                   //  33,554,432 B (dead after gemm_bt)
  u16* wib  = (u16*)(ws + 33554432);        //   8,388,608 B (permuted W_i)
  u16* whb  = (u16*)(ws + 41943040);        //   8,388,608 B
  u16* gxp  = (u16*)(ws + 50331648);        // 134,217,728 B
  u16* hbuf = (u16*)(ws + 184549376);       //     262,144 B (double buffer)
  u32* flags = (u32*)(ws + 184811520);      //       4,096 B

  cvt_x<<<M_, 256, 0, stream>>>(x, xb);
  cvt_w_perm<<<NG, 256, 0, stream>>>(wi, wib);
  cvt_w<<<4096, 256, 0, stream>>>(wh, whb);
  gemm_bt<<<dim3(NG / 128, M_ / 128), 256, 0, stream>>>(xb, wib, gxp);
  // zero flags AFTER gemm_bt (stream-ordered): kills stale values on replay
  (void)hipMemsetAsync(flags, 0, 4096, stream);

  void* args[] = { &whb, &gxp, &bi, &bh, &h0, &c0, &hbuf, &flags, &out };
  (void)hipLaunchCooperativeKernel((void*)lstm_rec, dim3(256), dim3(256), args, 0, stream);
}